// Round 9
// baseline (679.198 us; speedup 1.0000x reference)
//
#include <hip/hip_runtime.h>
#include <math.h>

#define B_  1024
#define S_  100
#define H_  256
#define L_  20000
#define U_  20000
#define EL_ 500000
#define EU_ 400000

typedef __bf16 bf16x8 __attribute__((ext_vector_type(8)));
typedef __bf16 bf16x4 __attribute__((ext_vector_type(4)));
typedef float  f32x4  __attribute__((ext_vector_type(4)));
typedef _Float16 f16x8 __attribute__((ext_vector_type(8)));
typedef _Float16 f16x2 __attribute__((ext_vector_type(2)));

// ---------------- flags for needed user rows ----------------
__global__ void k_mark(const int* __restrict__ uid, int* __restrict__ flags) {
    int i = blockIdx.x * blockDim.x + threadIdx.x;
    if (i < B_) flags[uid[i]] = 1;
}

// ---------------- CSR build: fused histograms (loc + flag-filtered usr) ----------------
__global__ void k_hist2(const int* __restrict__ rowL, const int* __restrict__ rowU,
                        const int* __restrict__ flags,
                        int* __restrict__ cntL, int* __restrict__ cntU) {
    int e = blockIdx.x * blockDim.x + threadIdx.x;
    if (e < EL_) {
        atomicAdd(&cntL[rowL[e]], 1);
    } else if (e < EL_ + EU_) {
        int r = rowU[e - EL_];
        if (flags[r]) atomicAdd(&cntU[r], 1);
    }
}

// ---------------- CSR build: dual single-block exclusive scans (block0=loc, block1=usr) ----------------
__global__ __launch_bounds__(1024) void k_scan2(const int* __restrict__ cntA,
                                                int* __restrict__ offsA, int* __restrict__ curA,
                                                const int* __restrict__ cntB,
                                                int* __restrict__ offsB, int* __restrict__ curB) {
    const int* cnt = blockIdx.x ? cntB : cntA;
    int* offs      = blockIdx.x ? offsB : offsA;
    int* cursor    = blockIdx.x ? curB : curA;
    __shared__ int wsum[16];
    __shared__ int carry_s;
    int tid = threadIdx.x;
    int lane = tid & 63, wv = tid >> 6;
    if (tid == 0) carry_s = 0;
    __syncthreads();
    for (int base = 0; base < L_; base += 1024) {
        int v = (base + tid < L_) ? cnt[base + tid] : 0;
        int x = v;
#pragma unroll
        for (int off = 1; off < 64; off <<= 1) {
            int y = __shfl_up(x, off, 64);
            if (lane >= off) x += y;
        }
        if (lane == 63) wsum[wv] = x;
        __syncthreads();
        if (wv == 0) {
            int s = (lane < 16) ? wsum[lane] : 0;
#pragma unroll
            for (int off = 1; off < 16; off <<= 1) {
                int y = __shfl_up(s, off, 64);
                if (lane >= off) s += y;
            }
            if (lane < 16) wsum[lane] = s;
        }
        __syncthreads();
        int excl = x - v + (wv ? wsum[wv - 1] : 0) + carry_s;
        if (base + tid < L_) { offs[base + tid] = excl; cursor[base + tid] = excl; }
        __syncthreads();
        if (tid == 0) carry_s += wsum[15];
        __syncthreads();
    }
    if (tid == 0) offs[L_] = carry_s;
}

// ---------------- CSR build: fused edge placement ----------------
__global__ void k_place2(const int* __restrict__ rowL, const int* __restrict__ colL,
                         const float* __restrict__ valL, int* __restrict__ curL,
                         int* __restrict__ colLs, float* __restrict__ valLs,
                         const int* __restrict__ rowU, const int* __restrict__ colU,
                         const float* __restrict__ valU, const int* __restrict__ flags,
                         int* __restrict__ curU, int* __restrict__ colUs,
                         float* __restrict__ valUs) {
    int e = blockIdx.x * blockDim.x + threadIdx.x;
    if (e < EL_) {
        int pos = atomicAdd(&curL[rowL[e]], 1);
        colLs[pos] = colL[e];
        valLs[pos] = valL[e];
    } else if (e < EL_ + EU_) {
        int e2 = e - EL_;
        int r = rowU[e2];
        if (!flags[r]) return;
        int pos = atomicAdd(&curU[r], 1);
        colUs[pos] = colU[e2];
        valUs[pos] = valU[e2];
    }
}

// ---------------- fused gather-accumulate: blocks [0,L) -> encw, [L, L+U) -> ewu ----------------
__global__ __launch_bounds__(256) void k_gather2(
        const int* __restrict__ offsL, const int* __restrict__ colLs,
        const float* __restrict__ valLs, float* __restrict__ encw,
        const int* __restrict__ offsU, const int* __restrict__ colUs,
        const float* __restrict__ valUs, float* __restrict__ ewu,
        const int* __restrict__ flags, const float* __restrict__ emb) {
    int r = blockIdx.x;
    const int* offs; const int* col_s; const float* val_s; float* out;
    if (r < L_) {
        offs = offsL; col_s = colLs; val_s = valLs; out = encw;
    } else {
        r -= L_;
        if (!flags[r]) return;
        offs = offsU; col_s = colUs; val_s = valUs; out = ewu;
    }
    int tid = threadIdx.x;
    int lo = offs[r], hi = offs[r + 1];
    float acc = 0.f;
    int i = lo;
    for (; i + 1 < hi; i += 2) {
        int c0 = col_s[i], c1 = col_s[i + 1];
        float v0 = val_s[i], v1 = val_s[i + 1];
        float e0 = emb[(long long)c0 * H_ + tid];
        float e1 = emb[(long long)c1 * H_ + tid];
        acc += v0 * e0 + v1 * e1;
    }
    if (i < hi) acc += val_s[i] * emb[(long long)col_s[i] * H_ + tid];
    out[(long long)r * H_ + tid] = acc;
}

// ---------------- f32 GEMM (EWW only): C = A @ B^T + bias ----------------
#define BM 128
#define BN 128
#define BK 16
#define PADW 132

__global__ __launch_bounds__(256) void k_gemm(
        const float* __restrict__ A, const float* __restrict__ Bm,
        const float* __restrict__ bias1, const float* __restrict__ bias2,
        float* __restrict__ C, int M, int N, int K) {
    __shared__ float As[BK][PADW];
    __shared__ float Bs[BK][PADW];
    int m0 = blockIdx.x * BM;
    int n0 = blockIdx.y * BN;
    int tid = threadIdx.x;
    int tn = tid & 15, tm = tid >> 4;

    float acc[8][8];
#pragma unroll
    for (int i = 0; i < 8; i++)
#pragma unroll
        for (int j = 0; j < 8; j++) acc[i][j] = 0.f;

    for (int k0 = 0; k0 < K; k0 += BK) {
#pragma unroll
        for (int h = 0; h < 2; h++) {
            int v = tid + h * 256;
            int rw = v >> 2, c4 = v & 3;
            int ar = m0 + rw; if (ar > M - 1) ar = M - 1;
            float4 a = *(const float4*)(A + (long long)ar * K + k0 + c4 * 4);
            As[c4 * 4 + 0][rw] = a.x; As[c4 * 4 + 1][rw] = a.y;
            As[c4 * 4 + 2][rw] = a.z; As[c4 * 4 + 3][rw] = a.w;
            int br = n0 + rw; if (br > N - 1) br = N - 1;
            float4 b = *(const float4*)(Bm + (long long)br * K + k0 + c4 * 4);
            Bs[c4 * 4 + 0][rw] = b.x; Bs[c4 * 4 + 1][rw] = b.y;
            Bs[c4 * 4 + 2][rw] = b.z; Bs[c4 * 4 + 3][rw] = b.w;
        }
        __syncthreads();
#pragma unroll
        for (int kk = 0; kk < BK; kk++) {
            float4 a0 = *(const float4*)&As[kk][tm * 8];
            float4 a1 = *(const float4*)&As[kk][tm * 8 + 4];
            float4 b0 = *(const float4*)&Bs[kk][tn * 8];
            float4 b1 = *(const float4*)&Bs[kk][tn * 8 + 4];
            float av[8] = {a0.x, a0.y, a0.z, a0.w, a1.x, a1.y, a1.z, a1.w};
            float bv[8] = {b0.x, b0.y, b0.z, b0.w, b1.x, b1.y, b1.z, b1.w};
#pragma unroll
            for (int i = 0; i < 8; i++)
#pragma unroll
                for (int j = 0; j < 8; j++) acc[i][j] += av[i] * bv[j];
        }
        __syncthreads();
    }

    float bsum[8];
#pragma unroll
    for (int j = 0; j < 8; j++) {
        int n = n0 + tn * 8 + j;
        float bb = 0.f;
        if (n < N) {
            if (bias1) bb += bias1[n];
            if (bias2) bb += bias2[n];
        }
        bsum[j] = bb;
    }
#pragma unroll
    for (int i = 0; i < 8; i++) {
        int m = m0 + tm * 8 + i;
        if (m < M) {
#pragma unroll
            for (int j = 0; j < 8; j++) {
                int n = n0 + tn * 8 + j;
                if (n < N) C[(long long)m * N + n] = acc[i][j] + bsum[j];
            }
        }
    }
}

// ---------------- f32 -> bf16 conversion (vectorized) ----------------
__global__ __launch_bounds__(256) void k_cvt(const float4* __restrict__ src,
                                             bf16x4* __restrict__ dst, int n4) {
    int i = blockIdx.x * blockDim.x + threadIdx.x;
    if (i >= n4) return;
    float4 v = src[i];
    bf16x4 o;
    o[0] = (__bf16)v.x; o[1] = (__bf16)v.y; o[2] = (__bf16)v.z; o[3] = (__bf16)v.w;
    dst[i] = o;
}

// ---------------- bf16 MFMA GEMM: C[m,n] = A[m,:] . Bw[n,:] + bias[n] ----------------
__global__ __launch_bounds__(256) void k_gemm_bf16(
        const __bf16* __restrict__ A, const __bf16* __restrict__ Bw,
        const float* __restrict__ bias, float* __restrict__ C,
        int M, int N, int K) {
    __shared__ __bf16 Asl[128 * 32];
    __shared__ __bf16 Bsl[128 * 32];
    int tid = threadIdx.x;
    int lane = tid & 63, w = tid >> 6;
    int wm = w >> 1, wn = w & 1;
    int m0 = blockIdx.x * 128, n0 = blockIdx.y * 128;

    f32x4 acc[4][4];
#pragma unroll
    for (int i = 0; i < 4; i++)
#pragma unroll
        for (int j = 0; j < 4; j++) acc[i][j] = (f32x4){0.f, 0.f, 0.f, 0.f};

    int fm = lane & 15, fq = lane >> 4;

    for (int k0 = 0; k0 < K; k0 += 32) {
#pragma unroll
        for (int h = 0; h < 2; h++) {
            int c = h * 256 + w * 64 + lane;
            int r = c >> 2, qsw = c & 3;
            int q = qsw ^ ((r >> 1) & 3);
            const __bf16* gA = A + (long long)(m0 + r) * K + k0 + q * 8;
            __builtin_amdgcn_global_load_lds(
                (const __attribute__((address_space(1))) void*)gA,
                (__attribute__((address_space(3))) void*)(Asl + (h * 256 + w * 64) * 8),
                16, 0, 0);
            int br = n0 + r; if (br > N - 1) br = N - 1;
            const __bf16* gB = Bw + (long long)br * K + k0 + q * 8;
            __builtin_amdgcn_global_load_lds(
                (const __attribute__((address_space(1))) void*)gB,
                (__attribute__((address_space(3))) void*)(Bsl + (h * 256 + w * 64) * 8),
                16, 0, 0);
        }
        __syncthreads();

        bf16x8 af[4], bfr[4];
#pragma unroll
        for (int mi = 0; mi < 4; mi++) {
            int r = wm * 64 + mi * 16 + fm;
            int ch = r * 4 + (fq ^ ((r >> 1) & 3));
            af[mi] = *(const bf16x8*)(Asl + ch * 8);
        }
#pragma unroll
        for (int ni = 0; ni < 4; ni++) {
            int r = wn * 64 + ni * 16 + fm;
            int ch = r * 4 + (fq ^ ((r >> 1) & 3));
            bfr[ni] = *(const bf16x8*)(Bsl + ch * 8);
        }
#pragma unroll
        for (int mi = 0; mi < 4; mi++)
#pragma unroll
            for (int ni = 0; ni < 4; ni++)
                acc[mi][ni] = __builtin_amdgcn_mfma_f32_16x16x32_bf16(
                    af[mi], bfr[ni], acc[mi][ni], 0, 0, 0);
        __syncthreads();
    }

#pragma unroll
    for (int ni = 0; ni < 4; ni++) {
        int col = n0 + wn * 64 + ni * 16 + fm;
        if (col >= N) continue;
        float bb = bias[col];
#pragma unroll
        for (int mi = 0; mi < 4; mi++) {
            int row = m0 + wm * 64 + mi * 16 + fq * 4;
#pragma unroll
            for (int r = 0; r < 4; r++)
                C[(long long)(row + r) * N + col] = acc[mi][ni][r] + bb;
        }
    }
}

// ---------------- w_j and denom ----------------
__global__ __launch_bounds__(256) void k_simwj(
        const int* __restrict__ map, const int* __restrict__ length, const int* __restrict__ uid,
        const float* __restrict__ td_, const float* __restrict__ gd_,
        const float* __restrict__ encw, const float* __restrict__ ewu,
        float* __restrict__ wj, float* __restrict__ denom) {
    int b = blockIdx.x;
    __shared__ float up[H_];
    __shared__ float wjl[S_];
    int tid = threadIdx.x;
    int u = uid[b];
    up[tid] = ewu[(long long)u * H_ + tid];
    __syncthreads();
    int wv = tid >> 6, lane = tid & 63;
    int len = length[b];
    for (int s = wv; s < S_; s += 4) {
        int mi = map[b * S_ + s];
        float4 x = ((const float4*)(encw + (long long)mi * H_))[lane];
        float4 uu = *(const float4*)&up[lane * 4];
        float dx = uu.x - x.x, dy = uu.y - x.y, dz = uu.z - x.z, dw = uu.w - x.w;
        float d2 = dx * dx + dy * dy + dz * dz + dw * dw;
#pragma unroll
        for (int off = 32; off; off >>= 1) d2 += __shfl_xor(d2, off, 64);
        if (lane == 0) {
            float nrm = sqrtf(d2);
            float sim = expf(-nrm);
            float td = td_[b * S_ + s], gd = gd_[b * S_ + s];
            float aj = (cosf(td * 7.27220521664304e-05f) + 1.0f) * 0.5f *
                       expf(-td * 1.1574074074074073e-06f);
            float bj = expf(-gd * 1000.0f);
            float w = (aj * bj + 1e-10f) * sim;
            if (s >= len) w = 0.f;
            wjl[s] = w;
            wj[b * S_ + s] = w;
        }
    }
    __syncthreads();
    if (tid < 64) {
        float v = (tid < S_) ? wjl[tid] : 0.f;
        if (tid + 64 < S_) v += wjl[tid + 64];
#pragma unroll
        for (int off = 32; off; off >>= 1) v += __shfl_xor(v, off, 64);
        if (tid == 0) denom[b] = v;
    }
}

// ---------------- RNN via MFMA: 64 blocks x 16 batch rows, 16 waves (1024 thr) ----------------
// h_{t+1} = tanh(x_t + h_t @ W_hh^T); oacc[b][j] = sum_s wj[b][s] * h_s[b][j]
// 16 waves (measured best: latency-chain-bound, more waves/SIMD interleave chains).
// This round: (a) MFMA chain split 2x4-deep (acc/acc2 + one add) halves the MFMA
// dependency depth; (b) packed h-writes: lane pairs exchange hv via __shfl_xor
// (register-only), pack two adjacent cols into one f16x2, even lanes write a
// single b32 -> write count halves, 32-lane pattern = 2 lanes/bank (free).
// af reads are at the 8-cy data-volume floor (irreducible).
// Sync = verified single __syncthreads per step (double-buffered hbuf; barrier's
// implicit vmcnt(0) completes the 1-step-ahead x prefetch; xn->xc after barrier).
#define RNN_STRIDE 264   // f16 row stride: 528B = 132 dwords = 4 banks mod 32

__global__ __launch_bounds__(1024, 1) void k_rnn_mfma(
        const float* __restrict__ EWW, const float* __restrict__ Whh,
        const int* __restrict__ map, const float* __restrict__ wj,
        const float* __restrict__ h0g, float* __restrict__ out_acc) {
    __shared__ _Float16 hbuf[2][16 * RNN_STRIDE];
    __shared__ int   maps_s[S_ * 16];
    __shared__ float wjs_s[S_ * 16];

    int tid = threadIdx.x;
    int lane = tid & 63, w = tid >> 6;      // w in 0..15
    int fm = lane & 15, fq = lane >> 4;
    int b0 = blockIdx.x * 16;
    int col = w * 16 + fm;                  // this thread's output column

    // stage maps & wj for this block's 16 rows x 100 steps
    for (int i = tid; i < 16 * S_; i += 1024) {
        int m = i / S_, s = i - m * S_;
        maps_s[s * 16 + m] = map[(b0 + m) * S_ + s];
        wjs_s[s * 16 + m] = wj[(b0 + m) * S_ + s];
    }
    // stage h0 -> f16 A-layout hbuf[0][m][k] (first 256 threads)
    if (tid < 256) {
        int m = tid >> 4, seg = tid & 15;
        const float4* src = (const float4*)(h0g + (long long)(b0 + m) * H_ + seg * 16);
        float4 a = src[0], bq = src[1], cq = src[2], dq = src[3];
        f16x8 v0, v1;
        v0[0] = (_Float16)a.x;  v0[1] = (_Float16)a.y;  v0[2] = (_Float16)a.z;  v0[3] = (_Float16)a.w;
        v0[4] = (_Float16)bq.x; v0[5] = (_Float16)bq.y; v0[6] = (_Float16)bq.z; v0[7] = (_Float16)bq.w;
        v1[0] = (_Float16)cq.x; v1[1] = (_Float16)cq.y; v1[2] = (_Float16)cq.z; v1[3] = (_Float16)cq.w;
        v1[4] = (_Float16)dq.x; v1[5] = (_Float16)dq.y; v1[6] = (_Float16)dq.z; v1[7] = (_Float16)dq.w;
        *(f16x8*)(hbuf[0] + m * RNN_STRIDE + seg * 16) = v0;
        *(f16x8*)(hbuf[0] + m * RNN_STRIDE + seg * 16 + 8) = v1;
    }

    // W_hh B-fragments in registers: wf[c], B[n=col][k=c*32+fq*8+j]
    f16x8 wf[8];
    {
        const float* wrow = Whh + (long long)col * H_;
#pragma unroll
        for (int c = 0; c < 8; c++) {
            int k = c * 32 + fq * 8;
            float4 p = *(const float4*)(wrow + k);
            float4 q = *(const float4*)(wrow + k + 4);
            f16x8 v;
            v[0] = (_Float16)p.x; v[1] = (_Float16)p.y; v[2] = (_Float16)p.z; v[3] = (_Float16)p.w;
            v[4] = (_Float16)q.x; v[5] = (_Float16)q.y; v[6] = (_Float16)q.z; v[7] = (_Float16)q.w;
            wf[c] = v;
        }
    }

    float accv[4];
#pragma unroll
    for (int r = 0; r < 4; r++) accv[r] = 0.f;

    __syncthreads();   // maps/wj/h0 staged

    // prefetch x for s=0 (C-layout positions; bias already folded into EWW)
    float xc[4], xn[4];
#pragma unroll
    for (int r = 0; r < 4; r++)
        xc[r] = EWW[(long long)maps_s[0 * 16 + fq * 4 + r] * H_ + col];

    int evenlane = !(fm & 1);

    for (int s = 0; s < S_; s++) {
        const _Float16* hr = hbuf[s & 1];
        _Float16*       hw = hbuf[(s + 1) & 1];

        f32x4 acc = (f32x4){xc[0], xc[1], xc[2], xc[3]};
        f32x4 acc2 = (f32x4){0.f, 0.f, 0.f, 0.f};

        // issue x prefetch for s+1; drained by the end-of-step __syncthreads
        if (s + 1 < S_) {
#pragma unroll
            for (int r = 0; r < 4; r++)
                xn[r] = EWW[(long long)maps_s[(s + 1) * 16 + fq * 4 + r] * H_ + col];
        }

        f16x8 af[8];
#pragma unroll
        for (int c = 0; c < 8; c++)
            af[c] = *(const f16x8*)(hr + fm * RNN_STRIDE + c * 32 + fq * 8);

        // two independent 4-deep chains instead of one 8-deep chain
#pragma unroll
        for (int c = 0; c < 4; c++) {
            acc  = __builtin_amdgcn_mfma_f32_16x16x32_f16(af[c],     wf[c],     acc,  0, 0, 0);
            acc2 = __builtin_amdgcn_mfma_f32_16x16x32_f16(af[c + 4], wf[c + 4], acc2, 0, 0, 0);
        }
        acc = acc + acc2;

#pragma unroll
        for (int r = 0; r < 4; r++) {
            float t = acc[r];
            t = fminf(15.f, fmaxf(-15.f, t));
            float e = __expf(2.f * t);
            float hv = 1.f - 2.f / (e + 1.f);
            accv[r] += wjs_s[s * 16 + fq * 4 + r] * hv;
            // pack own + neighbor col into f16x2; even lanes write one b32
            float nb = __shfl_xor(hv, 1, 64);
            f16x2 hp;
            hp[0] = (_Float16)hv;
            hp[1] = (_Float16)nb;
            if (evenlane)
                *(f16x2*)(hw + (fq * 4 + r) * RNN_STRIDE + col) = hp;
        }

        // single barrier per step: hbuf[s&1] reads retired, hw writes visible,
        // and the x prefetch drained (vmcnt(0) is part of __syncthreads).
        __syncthreads();

#pragma unroll
        for (int r = 0; r < 4; r++) xc[r] = xn[r];
    }

#pragma unroll
    for (int r = 0; r < 4; r++)
        out_acc[(long long)(b0 + fq * 4 + r) * H_ + col] = accv[r];
}

// ---------------- feature build: [out_w, p_u, out_w2] -> bf16 directly ----------------
__global__ __launch_bounds__(256) void k_feat(
        const float* __restrict__ out_acc, const float* __restrict__ denom,
        const int* __restrict__ uid, const float* __restrict__ user_emb,
        const int* __restrict__ seq, const float* __restrict__ wj,
        const float* __restrict__ emb2, __bf16* __restrict__ featb) {
    int b = blockIdx.x, j = threadIdx.x;
    __shared__ float wjl[S_];
    __shared__ int sq[S_];
    if (j < S_) {
        wjl[j] = wj[b * S_ + j];
        sq[j] = seq[b * S_ + j];
    }
    __syncthreads();
    float inv = 1.f / denom[b];
    featb[(long long)b * 768 + j] = (__bf16)(out_acc[(long long)b * H_ + j] * inv);
    featb[(long long)b * 768 + 256 + j] = (__bf16)(user_emb[(long long)uid[b] * H_ + j]);
    float a2 = 0.f;
    for (int s = 0; s < S_; s++) a2 += wjl[s] * emb2[(long long)sq[s] * H_ + j];
    featb[(long long)b * 768 + 512 + j] = (__bf16)(a2 * inv);
}

extern "C" void kernel_launch(void* const* d_in, const int* in_sizes, int n_in,
                              void* d_out, int out_size, void* d_ws, size_t ws_size,
                              hipStream_t stream) {
    const int*   full_seq     = (const int*)d_in[0];
    const int*   full_seq_map = (const int*)d_in[1];
    const int*   length       = (const int*)d_in[2];
    const int*   user_id      = (const int*)d_in[3];
    const float* time_delta   = (const float*)d_in[4];
    const float* geo_delta    = (const float*)d_in[5];
    const float* enc_emb      = (const float*)d_in[6];
    const float* user_emb     = (const float*)d_in[7];
    const float* emb2         = (const float*)d_in[8];
    const int*   row_loc      = (const int*)d_in[9];
    const int*   col_loc      = (const int*)d_in[10];
    const float* vals_loc     = (const float*)d_in[11];
    const int*   row_usr      = (const int*)d_in[12];
    const int*   col_usr      = (const int*)d_in[13];
    const float* vals_usr     = (const float*)d_in[14];
    const float* W_ih         = (const float*)d_in[15];
    const float* W_hh         = (const float*)d_in[16];
    const float* b_ih         = (const float*)d_in[17];
    const float* b_hh         = (const float*)d_in[18];
    const float* W1           = (const float*)d_in[19];
    const float* b1           = (const float*)d_in[20];
    const float* h0g          = (const float*)d_in[21];
    float* out = (float*)d_out;

    float* ws = (float*)d_ws;
    size_t o = 0;
    int*   flags = (int*)(ws + o); o += U_;              // zeroed each run
    float* ewu   = ws + o; o += (size_t)U_ * H_;         // written only for flagged rows
    float* encw  = ws + o; o += (size_t)L_ * H_;
    float* EWW   = ws + o; o += (size_t)L_ * H_;
    float* wj    = ws + o; o += (size_t)B_ * S_;
    float* denom = ws + o; o += B_;
    float* oacc  = ws + o; o += (size_t)B_ * H_;
    // loc CSR scratch aliases the region past wj/denom/oacc (dead until k_simwj)
    size_t a = o;
    int*   cntL  = (int*)(ws + a); a += L_ + 1;
    int*   offsL = (int*)(ws + a); a += L_ + 1;
    int*   curL  = (int*)(ws + a); a += L_ + 1;
    int*   colLs = (int*)(ws + a); a += EL_;
    float* valLs = ws + a;         a += EL_;
    // usr CSR scratch lives inside EWW (EWW written only after gathers complete)
    int*   cntU  = (int*)EWW;
    int*   offsU = cntU + (U_ + 1);
    int*   curU  = offsU + (U_ + 1);
    int*   colUs = curU + (U_ + 1);
    float* valUs = (float*)(colUs + EU_);
    // bf16 staging aliases the front of ws (flags/ewu/encw dead by conversion time)
    __bf16* w1bf   = (__bf16*)ws;
    __bf16* featbf = (__bf16*)EWW;

    hipMemsetAsync(flags, 0, U_ * sizeof(int), stream);
    hipMemsetAsync(cntL, 0, (L_ + 1) * sizeof(int), stream);
    hipMemsetAsync(cntU, 0, (U_ + 1) * sizeof(int), stream);
    k_mark<<<(B_ + 255) / 256, 256, 0, stream>>>(user_id, flags);

    // fused CSR build for both graphs
    k_hist2<<<(EL_ + EU_ + 255) / 256, 256, 0, stream>>>(row_loc, row_usr, flags, cntL, cntU);
    k_scan2<<<2, 1024, 0, stream>>>(cntL, offsL, curL, cntU, offsU, curU);
    k_place2<<<(EL_ + EU_ + 255) / 256, 256, 0, stream>>>(
        row_loc, col_loc, vals_loc, curL, colLs, valLs,
        row_usr, col_usr, vals_usr, flags, curU, colUs, valUs);
    k_gather2<<<L_ + U_, 256, 0, stream>>>(offsL, colLs, valLs, encw,
                                           offsU, colUs, valUs, ewu, flags, enc_emb);

    k_gemm<<<dim3((L_ + BM - 1) / BM, (H_ + BN - 1) / BN), 256, 0, stream>>>(
        encw, W_ih, b_ih, b_hh, EWW, L_, H_, H_);
    k_simwj<<<B_, 256, 0, stream>>>(full_seq_map, length, user_id, time_delta,
                                    geo_delta, encw, ewu, wj, denom);
    k_rnn_mfma<<<B_ / 16, 1024, 0, stream>>>(EWW, W_hh, full_seq_map, wj, h0g, oacc);
    k_feat<<<B_, 256, 0, stream>>>(oacc, denom, user_id, user_emb, full_seq, wj, emb2, featbf);

    k_cvt<<<((L_ * 3 * H_ / 4) + 255) / 256, 256, 0, stream>>>(
        (const float4*)W1, (bf16x4*)w1bf, L_ * 3 * H_ / 4);

    k_gemm_bf16<<<dim3(B_ / 128, (L_ + 127) / 128), 256, 0, stream>>>(
        featbf, w1bf, b1, out, B_, L_, 3 * H_);
}

// Round 10
// 608.552 us; speedup vs baseline: 1.1161x; 1.1161x over previous
//
#include <hip/hip_runtime.h>
#include <math.h>

#define B_  1024
#define S_  100
#define H_  256
#define L_  20000
#define U_  20000
#define EL_ 500000
#define EU_ 400000

typedef float  f32x4  __attribute__((ext_vector_type(4)));
typedef _Float16 f16x8 __attribute__((ext_vector_type(8)));
typedef _Float16 f16x4 __attribute__((ext_vector_type(4)));

// ---------------- flags for needed user rows ----------------
__global__ void k_mark(const int* __restrict__ uid, int* __restrict__ flags) {
    int i = blockIdx.x * blockDim.x + threadIdx.x;
    if (i < B_) flags[uid[i]] = 1;
}

// ---------------- CSR build: fused histograms (loc + flag-filtered usr) ----------------
__global__ void k_hist2(const int* __restrict__ rowL, const int* __restrict__ rowU,
                        const int* __restrict__ flags,
                        int* __restrict__ cntL, int* __restrict__ cntU) {
    int e = blockIdx.x * blockDim.x + threadIdx.x;
    if (e < EL_) {
        atomicAdd(&cntL[rowL[e]], 1);
    } else if (e < EL_ + EU_) {
        int r = rowU[e - EL_];
        if (flags[r]) atomicAdd(&cntU[r], 1);
    }
}

// ---------------- CSR build: dual single-block exclusive scans (block0=loc, block1=usr) ----------------
__global__ __launch_bounds__(1024) void k_scan2(const int* __restrict__ cntA,
                                                int* __restrict__ offsA, int* __restrict__ curA,
                                                const int* __restrict__ cntB,
                                                int* __restrict__ offsB, int* __restrict__ curB) {
    const int* cnt = blockIdx.x ? cntB : cntA;
    int* offs      = blockIdx.x ? offsB : offsA;
    int* cursor    = blockIdx.x ? curB : curA;
    __shared__ int wsum[16];
    __shared__ int carry_s;
    int tid = threadIdx.x;
    int lane = tid & 63, wv = tid >> 6;
    if (tid == 0) carry_s = 0;
    __syncthreads();
    for (int base = 0; base < L_; base += 1024) {
        int v = (base + tid < L_) ? cnt[base + tid] : 0;
        int x = v;
#pragma unroll
        for (int off = 1; off < 64; off <<= 1) {
            int y = __shfl_up(x, off, 64);
            if (lane >= off) x += y;
        }
        if (lane == 63) wsum[wv] = x;
        __syncthreads();
        if (wv == 0) {
            int s = (lane < 16) ? wsum[lane] : 0;
#pragma unroll
            for (int off = 1; off < 16; off <<= 1) {
                int y = __shfl_up(s, off, 64);
                if (lane >= off) s += y;
            }
            if (lane < 16) wsum[lane] = s;
        }
        __syncthreads();
        int excl = x - v + (wv ? wsum[wv - 1] : 0) + carry_s;
        if (base + tid < L_) { offs[base + tid] = excl; cursor[base + tid] = excl; }
        __syncthreads();
        if (tid == 0) carry_s += wsum[15];
        __syncthreads();
    }
    if (tid == 0) offs[L_] = carry_s;
}

// ---------------- CSR build: fused edge placement ----------------
__global__ void k_place2(const int* __restrict__ rowL, const int* __restrict__ colL,
                         const float* __restrict__ valL, int* __restrict__ curL,
                         int* __restrict__ colLs, float* __restrict__ valLs,
                         const int* __restrict__ rowU, const int* __restrict__ colU,
                         const float* __restrict__ valU, const int* __restrict__ flags,
                         int* __restrict__ curU, int* __restrict__ colUs,
                         float* __restrict__ valUs) {
    int e = blockIdx.x * blockDim.x + threadIdx.x;
    if (e < EL_) {
        int pos = atomicAdd(&curL[rowL[e]], 1);
        colLs[pos] = colL[e];
        valLs[pos] = valL[e];
    } else if (e < EL_ + EU_) {
        int e2 = e - EL_;
        int r = rowU[e2];
        if (!flags[r]) return;
        int pos = atomicAdd(&curU[r], 1);
        colUs[pos] = colU[e2];
        valUs[pos] = valU[e2];
    }
}

// ---------------- fused gather-accumulate -> f16 outputs ----------------
// blocks [0,L) -> encwh, [L, L+U) -> ewuh (flag-selected). f32 accumulate, f16 store.
__global__ __launch_bounds__(256) void k_gather2(
        const int* __restrict__ offsL, const int* __restrict__ colLs,
        const float* __restrict__ valLs, _Float16* __restrict__ encwh,
        const int* __restrict__ offsU, const int* __restrict__ colUs,
        const float* __restrict__ valUs, _Float16* __restrict__ ewuh,
        const int* __restrict__ flags, const float* __restrict__ emb) {
    int r = blockIdx.x;
    const int* offs; const int* col_s; const float* val_s; _Float16* out;
    if (r < L_) {
        offs = offsL; col_s = colLs; val_s = valLs; out = encwh;
    } else {
        r -= L_;
        if (!flags[r]) return;
        offs = offsU; col_s = colUs; val_s = valUs; out = ewuh;
    }
    int tid = threadIdx.x;
    int lo = offs[r], hi = offs[r + 1];
    float acc = 0.f;
    int i = lo;
    for (; i + 1 < hi; i += 2) {
        int c0 = col_s[i], c1 = col_s[i + 1];
        float v0 = val_s[i], v1 = val_s[i + 1];
        float e0 = emb[(long long)c0 * H_ + tid];
        float e1 = emb[(long long)c1 * H_ + tid];
        acc += v0 * e0 + v1 * e1;
    }
    if (i < hi) acc += val_s[i] * emb[(long long)col_s[i] * H_ + tid];
    out[(long long)r * H_ + tid] = (_Float16)acc;
}

// ---------------- f32 -> f16 conversion (vectorized) ----------------
__global__ __launch_bounds__(256) void k_cvth(const float4* __restrict__ src,
                                              f16x4* __restrict__ dst, int n4) {
    int i = blockIdx.x * blockDim.x + threadIdx.x;
    if (i >= n4) return;
    float4 v = src[i];
    f16x4 o;
    o[0] = (_Float16)v.x; o[1] = (_Float16)v.y; o[2] = (_Float16)v.z; o[3] = (_Float16)v.w;
    dst[i] = o;
}

// ---------------- f16 MFMA GEMM: C[m,n] = A[m,:] . Bw[n,:] + bias1[n] (+bias2[n]) ----------------
// Templated output type: _Float16 (EWW) or float (final logits).
// OOB M-rows (EWW case, 20000..20095) write past the C region into scratch that
// is fully rewritten (wj by k_simwj) before any read -- verified ordering.
template <typename TO>
__global__ __launch_bounds__(256) void k_gemm_mfma(
        const _Float16* __restrict__ A, const _Float16* __restrict__ Bw,
        const float* __restrict__ bias1, const float* __restrict__ bias2,
        TO* __restrict__ C, int M, int N, int K) {
    __shared__ _Float16 Asl[128 * 32];
    __shared__ _Float16 Bsl[128 * 32];
    int tid = threadIdx.x;
    int lane = tid & 63, w = tid >> 6;
    int wm = w >> 1, wn = w & 1;
    int m0 = blockIdx.x * 128, n0 = blockIdx.y * 128;

    f32x4 acc[4][4];
#pragma unroll
    for (int i = 0; i < 4; i++)
#pragma unroll
        for (int j = 0; j < 4; j++) acc[i][j] = (f32x4){0.f, 0.f, 0.f, 0.f};

    int fm = lane & 15, fq = lane >> 4;

    for (int k0 = 0; k0 < K; k0 += 32) {
#pragma unroll
        for (int h = 0; h < 2; h++) {
            int c = h * 256 + w * 64 + lane;
            int r = c >> 2, qsw = c & 3;
            int q = qsw ^ ((r >> 1) & 3);
            const _Float16* gA = A + (long long)(m0 + r) * K + k0 + q * 8;
            __builtin_amdgcn_global_load_lds(
                (const __attribute__((address_space(1))) void*)gA,
                (__attribute__((address_space(3))) void*)(Asl + (h * 256 + w * 64) * 8),
                16, 0, 0);
            int br = n0 + r; if (br > N - 1) br = N - 1;
            const _Float16* gB = Bw + (long long)br * K + k0 + q * 8;
            __builtin_amdgcn_global_load_lds(
                (const __attribute__((address_space(1))) void*)gB,
                (__attribute__((address_space(3))) void*)(Bsl + (h * 256 + w * 64) * 8),
                16, 0, 0);
        }
        __syncthreads();

        f16x8 af[4], bfr[4];
#pragma unroll
        for (int mi = 0; mi < 4; mi++) {
            int r = wm * 64 + mi * 16 + fm;
            int ch = r * 4 + (fq ^ ((r >> 1) & 3));
            af[mi] = *(const f16x8*)(Asl + ch * 8);
        }
#pragma unroll
        for (int ni = 0; ni < 4; ni++) {
            int r = wn * 64 + ni * 16 + fm;
            int ch = r * 4 + (fq ^ ((r >> 1) & 3));
            bfr[ni] = *(const f16x8*)(Bsl + ch * 8);
        }
#pragma unroll
        for (int mi = 0; mi < 4; mi++)
#pragma unroll
            for (int ni = 0; ni < 4; ni++)
                acc[mi][ni] = __builtin_amdgcn_mfma_f32_16x16x32_f16(
                    af[mi], bfr[ni], acc[mi][ni], 0, 0, 0);
        __syncthreads();
    }

#pragma unroll
    for (int ni = 0; ni < 4; ni++) {
        int col = n0 + wn * 64 + ni * 16 + fm;
        if (col >= N) continue;
        float bb = bias1 ? bias1[col] : 0.f;
        if (bias2) bb += bias2[col];
#pragma unroll
        for (int mi = 0; mi < 4; mi++) {
            int row = m0 + wm * 64 + mi * 16 + fq * 4;
#pragma unroll
            for (int r = 0; r < 4; r++)
                C[(long long)(row + r) * N + col] = (TO)(acc[mi][ni][r] + bb);
        }
    }
}

// ---------------- w_j and denom (f16 encw/ewu inputs) ----------------
__global__ __launch_bounds__(256) void k_simwj(
        const int* __restrict__ map, const int* __restrict__ length, const int* __restrict__ uid,
        const float* __restrict__ td_, const float* __restrict__ gd_,
        const _Float16* __restrict__ encwh, const _Float16* __restrict__ ewuh,
        float* __restrict__ wj, float* __restrict__ denom) {
    int b = blockIdx.x;
    __shared__ float up[H_];
    __shared__ float wjl[S_];
    int tid = threadIdx.x;
    int u = uid[b];
    up[tid] = (float)ewuh[(long long)u * H_ + tid];
    __syncthreads();
    int wv = tid >> 6, lane = tid & 63;
    int len = length[b];
    for (int s = wv; s < S_; s += 4) {
        int mi = map[b * S_ + s];
        f16x4 xr = *(const f16x4*)(encwh + (long long)mi * H_ + lane * 4);
        float4 uu = *(const float4*)&up[lane * 4];
        float dx = uu.x - (float)xr[0], dy = uu.y - (float)xr[1];
        float dz = uu.z - (float)xr[2], dw = uu.w - (float)xr[3];
        float d2 = dx * dx + dy * dy + dz * dz + dw * dw;
#pragma unroll
        for (int off = 32; off; off >>= 1) d2 += __shfl_xor(d2, off, 64);
        if (lane == 0) {
            float nrm = sqrtf(d2);
            float sim = expf(-nrm);
            float td = td_[b * S_ + s], gd = gd_[b * S_ + s];
            float aj = (cosf(td * 7.27220521664304e-05f) + 1.0f) * 0.5f *
                       expf(-td * 1.1574074074074073e-06f);
            float bj = expf(-gd * 1000.0f);
            float w = (aj * bj + 1e-10f) * sim;
            if (s >= len) w = 0.f;
            wjl[s] = w;
            wj[b * S_ + s] = w;
        }
    }
    __syncthreads();
    if (tid < 64) {
        float v = (tid < S_) ? wjl[tid] : 0.f;
        if (tid + 64 < S_) v += wjl[tid + 64];
#pragma unroll
        for (int off = 32; off; off >>= 1) v += __shfl_xor(v, off, 64);
        if (tid == 0) denom[b] = v;
    }
}

// ---------------- RNN via MFMA: 64 blocks x 16 batch rows, 16 waves (1024 thr) ----------------
// Exact round-5 structure (measured best: 106 us). Only change: x loads read the
// f16 EWW (halves FETCH; EWW=10MB now fits aggregate L2). Wave w owns cols
// w*16+fm; single __syncthreads per step; double-buffered hbuf; the barrier's
// implicit vmcnt(0) completes the 1-step-ahead x prefetch; xn->xc after barrier.
#define RNN_STRIDE 264   // f16 row stride: 528B = 132 dwords = 4 banks mod 32

__global__ __launch_bounds__(1024, 1) void k_rnn_mfma(
        const _Float16* __restrict__ EWWh, const float* __restrict__ Whh,
        const int* __restrict__ map, const float* __restrict__ wj,
        const float* __restrict__ h0g, float* __restrict__ out_acc) {
    __shared__ _Float16 hbuf[2][16 * RNN_STRIDE];
    __shared__ int   maps_s[S_ * 16];
    __shared__ float wjs_s[S_ * 16];

    int tid = threadIdx.x;
    int lane = tid & 63, w = tid >> 6;      // w in 0..15
    int fm = lane & 15, fq = lane >> 4;
    int b0 = blockIdx.x * 16;
    int col = w * 16 + fm;                  // this thread's output column

    // stage maps & wj for this block's 16 rows x 100 steps
    for (int i = tid; i < 16 * S_; i += 1024) {
        int m = i / S_, s = i - m * S_;
        maps_s[s * 16 + m] = map[(b0 + m) * S_ + s];
        wjs_s[s * 16 + m] = wj[(b0 + m) * S_ + s];
    }
    // stage h0 -> f16 A-layout hbuf[0][m][k] (first 256 threads)
    if (tid < 256) {
        int m = tid >> 4, seg = tid & 15;
        const float4* src = (const float4*)(h0g + (long long)(b0 + m) * H_ + seg * 16);
        float4 a = src[0], bq = src[1], cq = src[2], dq = src[3];
        f16x8 v0, v1;
        v0[0] = (_Float16)a.x;  v0[1] = (_Float16)a.y;  v0[2] = (_Float16)a.z;  v0[3] = (_Float16)a.w;
        v0[4] = (_Float16)bq.x; v0[5] = (_Float16)bq.y; v0[6] = (_Float16)bq.z; v0[7] = (_Float16)bq.w;
        v1[0] = (_Float16)cq.x; v1[1] = (_Float16)cq.y; v1[2] = (_Float16)cq.z; v1[3] = (_Float16)cq.w;
        v1[4] = (_Float16)dq.x; v1[5] = (_Float16)dq.y; v1[6] = (_Float16)dq.z; v1[7] = (_Float16)dq.w;
        *(f16x8*)(hbuf[0] + m * RNN_STRIDE + seg * 16) = v0;
        *(f16x8*)(hbuf[0] + m * RNN_STRIDE + seg * 16 + 8) = v1;
    }

    // W_hh B-fragments in registers: wf[c], B[n=col][k=c*32+fq*8+j]
    f16x8 wf[8];
    {
        const float* wrow = Whh + (long long)col * H_;
#pragma unroll
        for (int c = 0; c < 8; c++) {
            int k = c * 32 + fq * 8;
            float4 p = *(const float4*)(wrow + k);
            float4 q = *(const float4*)(wrow + k + 4);
            f16x8 v;
            v[0] = (_Float16)p.x; v[1] = (_Float16)p.y; v[2] = (_Float16)p.z; v[3] = (_Float16)p.w;
            v[4] = (_Float16)q.x; v[5] = (_Float16)q.y; v[6] = (_Float16)q.z; v[7] = (_Float16)q.w;
            wf[c] = v;
        }
    }

    float accv[4];
#pragma unroll
    for (int r = 0; r < 4; r++) accv[r] = 0.f;

    __syncthreads();   // maps/wj/h0 staged

    // prefetch x for s=0 (C-layout positions; bias already folded into EWW)
    float xc[4], xn[4];
#pragma unroll
    for (int r = 0; r < 4; r++)
        xc[r] = (float)EWWh[(long long)maps_s[0 * 16 + fq * 4 + r] * H_ + col];

    for (int s = 0; s < S_; s++) {
        const _Float16* hr = hbuf[s & 1];
        _Float16*       hw = hbuf[(s + 1) & 1];

        f32x4 acc = (f32x4){xc[0], xc[1], xc[2], xc[3]};

        // issue x prefetch for s+1; drained by the end-of-step __syncthreads
        if (s + 1 < S_) {
#pragma unroll
            for (int r = 0; r < 4; r++)
                xn[r] = (float)EWWh[(long long)maps_s[(s + 1) * 16 + fq * 4 + r] * H_ + col];
        }

        f16x8 af[8];
#pragma unroll
        for (int c = 0; c < 8; c++)
            af[c] = *(const f16x8*)(hr + fm * RNN_STRIDE + c * 32 + fq * 8);
#pragma unroll
        for (int c = 0; c < 8; c++)
            acc = __builtin_amdgcn_mfma_f32_16x16x32_f16(af[c], wf[c], acc, 0, 0, 0);

#pragma unroll
        for (int r = 0; r < 4; r++) {
            float t = acc[r];
            t = fminf(15.f, fmaxf(-15.f, t));
            float e = __expf(2.f * t);
            float hv = 1.f - 2.f / (e + 1.f);
            accv[r] += wjs_s[s * 16 + fq * 4 + r] * hv;
            hw[(fq * 4 + r) * RNN_STRIDE + col] = (_Float16)hv;
        }

        // single barrier per step: hbuf[s&1] reads retired, hw writes visible,
        // and the x prefetch drained (vmcnt(0) is part of __syncthreads).
        __syncthreads();

#pragma unroll
        for (int r = 0; r < 4; r++) xc[r] = xn[r];
    }

#pragma unroll
    for (int r = 0; r < 4; r++)
        out_acc[(long long)(b0 + fq * 4 + r) * H_ + col] = accv[r];
}

// ---------------- feature build: [out_w, p_u, out_w2] -> f16 directly ----------------
__global__ __launch_bounds__(256) void k_feat(
        const float* __restrict__ out_acc, const float* __restrict__ denom,
        const int* __restrict__ uid, const float* __restrict__ user_emb,
        const int* __restrict__ seq, const float* __restrict__ wj,
        const float* __restrict__ emb2, _Float16* __restrict__ feath) {
    int b = blockIdx.x, j = threadIdx.x;
    __shared__ float wjl[S_];
    __shared__ int sq[S_];
    if (j < S_) {
        wjl[j] = wj[b * S_ + j];
        sq[j] = seq[b * S_ + j];
    }
    __syncthreads();
    float inv = 1.f / denom[b];
    feath[(long long)b * 768 + j] = (_Float16)(out_acc[(long long)b * H_ + j] * inv);
    feath[(long long)b * 768 + 256 + j] = (_Float16)(user_emb[(long long)uid[b] * H_ + j]);
    float a2 = 0.f;
    for (int s = 0; s < S_; s++) a2 += wjl[s] * emb2[(long long)sq[s] * H_ + j];
    feath[(long long)b * 768 + 512 + j] = (_Float16)(a2 * inv);
}

extern "C" void kernel_launch(void* const* d_in, const int* in_sizes, int n_in,
                              void* d_out, int out_size, void* d_ws, size_t ws_size,
                              hipStream_t stream) {
    const int*   full_seq     = (const int*)d_in[0];
    const int*   full_seq_map = (const int*)d_in[1];
    const int*   length       = (const int*)d_in[2];
    const int*   user_id      = (const int*)d_in[3];
    const float* time_delta   = (const float*)d_in[4];
    const float* geo_delta    = (const float*)d_in[5];
    const float* enc_emb      = (const float*)d_in[6];
    const float* user_emb     = (const float*)d_in[7];
    const float* emb2         = (const float*)d_in[8];
    const int*   row_loc      = (const int*)d_in[9];
    const int*   col_loc      = (const int*)d_in[10];
    const float* vals_loc     = (const float*)d_in[11];
    const int*   row_usr      = (const int*)d_in[12];
    const int*   col_usr      = (const int*)d_in[13];
    const float* vals_usr     = (const float*)d_in[14];
    const float* W_ih         = (const float*)d_in[15];
    const float* W_hh         = (const float*)d_in[16];
    const float* b_ih         = (const float*)d_in[17];
    const float* b_hh         = (const float*)d_in[18];
    const float* W1           = (const float*)d_in[19];
    const float* b1           = (const float*)d_in[20];
    const float* h0g          = (const float*)d_in[21];
    float* out = (float*)d_out;

    float* ws = (float*)d_ws;
    size_t o = 0;
    int*      flags = (int*)(ws + o);      o += U_;                  // zeroed each run
    _Float16* ewuh  = (_Float16*)(ws + o); o += (size_t)U_ * H_ / 2; // f16, flagged rows only
    _Float16* encwh = (_Float16*)(ws + o); o += (size_t)L_ * H_ / 2; // f16
    _Float16* ewwh  = (_Float16*)(ws + o); o += (size_t)L_ * H_ / 2; // f16 (GEMM OOB rows spill into wj: rewritten by k_simwj before any read)
    float* wj    = ws + o; o += (size_t)B_ * S_;
    float* denom = ws + o; o += B_;
    float* oacc  = ws + o; o += (size_t)B_ * H_;
    _Float16* feath = (_Float16*)(ws + o); o += (size_t)B_ * 3 * H_ / 2;
    _Float16* wihh  = (_Float16*)(ws + o); o += (size_t)H_ * H_ / 2;
    // loc CSR scratch: own space after the above (alive only through k_gather2)
    size_t a = o;
    int*   cntL  = (int*)(ws + a); a += L_ + 4;
    int*   offsL = (int*)(ws + a); a += L_ + 4;
    int*   curL  = (int*)(ws + a); a += L_ + 4;
    int*   colLs = (int*)(ws + a); a += EL_;
    float* valLs = ws + a;         a += EL_;
    // usr CSR scratch lives inside the ewwh region (ewwh written only after gathers)
    int*   cntU  = (int*)ewwh;
    int*   offsU = cntU + (U_ + 4);
    int*   curU  = offsU + (U_ + 4);
    int*   colUs = curU + (U_ + 4);
    float* valUs = (float*)(colUs + EU_);
    // W1 f16 staging aliases the front of ws: flags/ewuh/encwh/ewwh (7.70M floats)
    // are all dead by k_cvth(W1) time (simwj + rnn done); w1h needs 7.68M floats.
    _Float16* w1h = (_Float16*)ws;

    hipMemsetAsync(flags, 0, U_ * sizeof(int), stream);
    hipMemsetAsync(cntL, 0, (L_ + 1) * sizeof(int), stream);
    hipMemsetAsync(cntU, 0, (U_ + 1) * sizeof(int), stream);
    k_mark<<<(B_ + 255) / 256, 256, 0, stream>>>(user_id, flags);

    // fused CSR build for both graphs
    k_hist2<<<(EL_ + EU_ + 255) / 256, 256, 0, stream>>>(row_loc, row_usr, flags, cntL, cntU);
    k_scan2<<<2, 1024, 0, stream>>>(cntL, offsL, curL, cntU, offsU, curU);
    k_place2<<<(EL_ + EU_ + 255) / 256, 256, 0, stream>>>(
        row_loc, col_loc, vals_loc, curL, colLs, valLs,
        row_usr, col_usr, vals_usr, flags, curU, colUs, valUs);
    k_gather2<<<L_ + U_, 256, 0, stream>>>(offsL, colLs, valLs, encwh,
                                           offsU, colUs, valUs, ewuh, flags, enc_emb);

    // EWW = encw @ W_ih^T + (b_ih + b_hh), f16 in / f16 out via MFMA
    k_cvth<<<((H_ * H_ / 4) + 255) / 256, 256, 0, stream>>>(
        (const float4*)W_ih, (f16x4*)wihh, H_ * H_ / 4);
    k_gemm_mfma<_Float16><<<dim3((L_ + 127) / 128, H_ / 128), 256, 0, stream>>>(
        encwh, wihh, b_ih, b_hh, ewwh, L_, H_, H_);

    k_simwj<<<B_, 256, 0, stream>>>(full_seq_map, length, user_id, time_delta,
                                    geo_delta, encwh, ewuh, wj, denom);
    k_rnn_mfma<<<B_ / 16, 1024, 0, stream>>>(ewwh, W_hh, full_seq_map, wj, h0g, oacc);
    k_feat<<<B_, 256, 0, stream>>>(oacc, denom, user_id, user_emb, full_seq, wj, emb2, feath);

    k_cvth<<<((L_ * 3 * H_ / 4) + 255) / 256, 256, 0, stream>>>(
        (const float4*)W1, (f16x4*)w1h, L_ * 3 * H_ / 4);

    k_gemm_mfma<float><<<dim3(B_ / 128, (L_ + 127) / 128), 256, 0, stream>>>(
        feath, w1h, b1, nullptr, out, B_, L_, 3 * H_);
}